// Round 9
// baseline (39101.477 us; speedup 1.0000x reference)
//
#include <hip/hip_runtime.h>
#include <stdint.h>

// SequentialFeedForward: autoregressive 6-layer MLP, L=2048 steps.
// R9: R4 champion + tag-summary detection. Producers write one summary tag
// word per block (64 words = 2 lines per buffer). Consumers' wave0 polls the
// 2-line summary (1 coalesced load + __all) instead of sweeping the 64-line
// record array; on pass, ONE R4-style checked sweep fetches payload (per-
// record tags still verify -> summary race benign). Failed-poll line
// coverage drops 32x. Probe (R8) measured single-flag T_hop ~0.3us; this
// tests whether R4's 2.45us hop excess is poll-coverage congestion.

typedef uint32_t u32;
typedef _Float16 half_t;
typedef _Float16 half2_t __attribute__((ext_vector_type(2)));

#define L_SEQ 2048
#define WIDTH 2048
#define WS    32
#define NAA   21
#define INS   704   // WS*NAA + WS
#define NB    256
#define SLP_FAIL 2  // ~128 cy per failed poll sweep
#define SLP_IDLE 20 // ~0.53 us per unit
#define N_IDLE   3  // idle sleeps after emit (~1.6 us)

__device__ __forceinline__ float h2f(u32 b){
  union { unsigned short u; half_t h; } c; c.u = (unsigned short)(b & 0xffffu);
  return (float)c.h;
}
__device__ __forceinline__ u32 f2h(float f){
  union { unsigned short u; half_t h; } c; c.h = (half_t)f;
  return (u32)c.u;
}
__device__ __forceinline__ float fdot2f(u32 a, u32 b, float c){
#if __has_builtin(__builtin_amdgcn_fdot2)
  union { u32 u; half2_t v; } ca, cb; ca.u = a; cb.u = b;
  return __builtin_amdgcn_fdot2(ca.v, cb.v, c, false);
#else
  return c + h2f(a)*h2f(b) + h2f(a>>16)*h2f(b>>16);
#endif
}
__device__ __forceinline__ u32 aload(const u32* p){
  return __hip_atomic_load(const_cast<u32*>(p), __ATOMIC_RELAXED, __HIP_MEMORY_SCOPE_AGENT);
}
__device__ __forceinline__ void astore(u32* p, u32 v){
  __hip_atomic_store(p, v, __ATOMIC_RELAXED, __HIP_MEMORY_SCOPE_AGENT);
}

// ---- pre-pass: transpose W0 (for coalesced c0 gather) ----
__global__ void k_wt(const float* __restrict__ W0, float* __restrict__ W0T){
  int tid = blockIdx.x*256 + threadIdx.x;
  if (tid < INS*WIDTH){
    int c = tid >> 11, i = tid & 2047;
    W0T[(size_t)c*WIDTH + i] = W0[(size_t)i*INS + c];
  }
}

// ---- pre-pass: W1..W4 fp32 -> fp16 ----
// Wp[(l*2048+r)*256 + j] uint4: comp q = half2(W[r][256*(2q)+j], W[r][256*(2q+1)+j])
__global__ void k_wc(const float* __restrict__ A, const float* __restrict__ B,
                     const float* __restrict__ C, const float* __restrict__ D,
                     uint4* __restrict__ Wp){
  int b = blockIdx.x; int l = b >> 11; int r = b & 2047; int j = threadIdx.x;
  const float* S = (l==0)?A:(l==1)?B:(l==2)?C:D;
  const float* row = S + (size_t)r*WIDTH;
  u32 o[4];
  #pragma unroll
  for (int q=0;q<4;++q)
    o[q] = f2h(row[256*(2*q)+j]) | (f2h(row[256*(2*q+1)+j]) << 16);
  Wp[(size_t)b*256 + j] = make_uint4(o[0],o[1],o[2],o[3]);
}

// ---- pre-pass: c0[t][col] = b0 + one-hot gather; thread j owns cols {256k+j} ----
__global__ void k_c0(const int* __restrict__ x, const float* __restrict__ W0T,
                     const float* __restrict__ b0, uint4* __restrict__ c0p){
  int t = blockIdx.x, j = threadIdx.x;
  __shared__ int cidx[WS];
  if (j < WS){
    int s = t - (WS-1) + j;
    cidx[j] = (s >= 0) ? (NAA*j + x[s]) : -1;
  }
  __syncthreads();
  float acc[8];
  #pragma unroll
  for (int k=0;k<8;++k) acc[k] = b0[256*k + j];
  for (int m=0;m<WS;++m){
    int c = cidx[m];
    if (c >= 0){
      const float* col = W0T + (size_t)c*WIDTH;
      #pragma unroll
      for (int k=0;k<8;++k) acc[k] += col[256*k + j];
    }
  }
  u32 o[4];
  #pragma unroll
  for (int q=0;q<4;++q) o[q] = f2h(acc[2*q]) | (f2h(acc[2*q+1]) << 16);
  c0p[(size_t)t*256 + j] = make_uint4(o[0],o[1],o[2],o[3]);
}

// ---- pre-pass: window weights, packed for G0's idle-window streaming ----
__global__ void k_wy(const float* __restrict__ W0, u32* __restrict__ wyb){
  int b = blockIdx.x; int k = b >> 4, p = b & 15; int j = threadIdx.x;
  int col = 256*k + j;
  float a = W0[(size_t)col*INS + (INS-WS) + 2*p];
  float c = W0[(size_t)col*INS + (INS-WS) + 2*p + 1];
  wyb[(size_t)b*256 + j] = f2h(a) | (f2h(c) << 16);
}

// ---- pre-pass: reset exchange buffers + tag summaries (every launch) ----
__global__ void k_reset(u32* __restrict__ hb, u32* __restrict__ tsum){
  int tid = blockIdx.x*256 + threadIdx.x;
  if (tid < 4*WIDTH) hb[tid] = 0xFFFFFFFFu;
  if (tid < 256)     tsum[tid] = 0xFFFFFFFFu;   // 4 groups x 64 tags
}

// ---- main persistent dataflow kernel ----
__global__ __launch_bounds__(256, 1) void k_main(
    const float* __restrict__ W0,
    const float* __restrict__ b1, const float* __restrict__ b2,
    const float* __restrict__ b3, const float* __restrict__ b4,
    const float* __restrict__ W5, const float* __restrict__ b5p,
    const uint4* __restrict__ Wp, const uint4* __restrict__ c0p,
    const u32* __restrict__ wyb,
    u32* hb, u32* tsum, float* __restrict__ out)
{
  const int j  = threadIdx.x;
  const int X  = blockIdx.x;
  const int g  = X >> 6;      // stage group 0..3
  const int Xl = X & 63;      // block within group
  const int lw = j & 63;
  const int w  = j >> 6;

  __shared__ float red[4][32];
  __shared__ float redp[4];

  // stage weight slice: rows 32*Xl .. 32*Xl+31 of W_{g+1}
  uint4 wreg[32];
  #pragma unroll
  for (int r=0;r<32;++r)
    wreg[r] = Wp[((size_t)g*2048 + 32*Xl + r)*256 + j];

  const float* bp = (g==0)?b1:(g==1)?b2:(g==2)?b3:b4;
  float bv = 0.f;
  if (j < 32) bv = bp[32*Xl + j];

  u32 hh[4];

  auto doreduce_emit = [&](u32 tag){
    float c32[32];
    #pragma unroll
    for (int r=0;r<32;++r){
      float a = 0.f;
      a = fdot2f(wreg[r].x, hh[0], a);
      a = fdot2f(wreg[r].y, hh[1], a);
      a = fdot2f(wreg[r].z, hh[2], a);
      a = fdot2f(wreg[r].w, hh[3], a);
      c32[r] = a;
    }
    float c16[16];
    #pragma unroll
    for (int i=0;i<16;++i){
      float v = c32[2*i]   + __shfl_xor(c32[2*i],   1);
      float u = c32[2*i+1] + __shfl_xor(c32[2*i+1], 1);
      c16[i] = (lw & 1) ? u : v;
    }
    float c8[8];
    #pragma unroll
    for (int i=0;i<8;++i){
      float v = c16[2*i]   + __shfl_xor(c16[2*i],   2);
      float u = c16[2*i+1] + __shfl_xor(c16[2*i+1], 2);
      c8[i] = (lw & 2) ? u : v;
    }
    float c4[4];
    #pragma unroll
    for (int i=0;i<4;++i){
      float v = c8[2*i]   + __shfl_xor(c8[2*i],   4);
      float u = c8[2*i+1] + __shfl_xor(c8[2*i+1], 4);
      c4[i] = (lw & 4) ? u : v;
    }
    float c2[2];
    #pragma unroll
    for (int i=0;i<2;++i){
      float v = c4[2*i]   + __shfl_xor(c4[2*i],   8);
      float u = c4[2*i+1] + __shfl_xor(c4[2*i+1], 8);
      c2[i] = (lw & 8) ? u : v;
    }
    float v1 = c2[0] + __shfl_xor(c2[0], 16);
    float u1 = c2[1] + __shfl_xor(c2[1], 16);
    float c1 = (lw & 16) ? u1 : v1;
    float tot = c1 + __shfl_xor(c1, 32);
    if (lw < 32) red[w][lw] = tot;
    __syncthreads();
    if (j < 32){
      float s = fmaxf(red[0][j]+red[1][j]+red[2][j]+red[3][j] + bv, 0.f);
      astore(&hb[(size_t)g*WIDTH + 32*Xl + j], (tag << 16) | f2h(s));
    }
    if (j == 0) astore(&tsum[(size_t)g*64 + Xl], tag);  // summary hint
    __syncthreads();
  };

  // wave0 polls the 64-word summary (2 lines); others wait at the barrier
  auto pollsum = [&](const u32* tp, u32 tag){
    if (w == 0){
      for(;;){
        u32 tv = aload(tp + lw);
        if (__all((int)(tv == tag))) break;
        __builtin_amdgcn_s_sleep(SLP_FAIL);
      }
    }
    __syncthreads();
  };

  // checked payload sweep (R4-style; normally 1 iteration after summary-pass)
  auto pollh = [&](int gin, u32 tag){
    u32 rec[8];
    const u32* base = hb + (size_t)gin*WIDTH;
    for(;;){
      #pragma unroll
      for (int k=0;k<8;++k) rec[k] = aload(base + 256*k + j);
      bool ok = true;
      #pragma unroll
      for (int k=0;k<8;++k) ok &= ((rec[k] >> 16) == tag);
      if (ok) break;
      __builtin_amdgcn_s_sleep(SLP_FAIL);
    }
    #pragma unroll
    for (int q=0;q<4;++q) hh[q] = (rec[2*q] & 0xffffu) | (rec[2*q+1] << 16);
  };

  // stagger pipeline-fill polling
  for (int i=0;i<g;++i) __builtin_amdgcn_s_sleep(SLP_IDLE);

  if (g > 0){
    const int gin = g - 1;
    const u32* tp = tsum + (size_t)gin*64;
    #pragma unroll 1
    for (int t=0; t<L_SEQ; ++t){
      pollsum(tp, (u32)t);
      pollh(gin, (u32)t);
      doreduce_emit((u32)t);
      for (int i=0;i<N_IDLE;++i) __builtin_amdgcn_s_sleep(SLP_IDLE);
    }
  } else {
    // ---- G0: y-reduction + h0 + layer 1 ----
    float w5f[8], w31v[8];
    #pragma unroll
    for (int k=0;k<8;++k){
      w5f[k]  = W5[256*k + j];
      w31v[k] = W0[(size_t)(256*k + j)*INS + (INS-1)];
    }
    const float b5v = b5p[0];
    u32 yqp[16];
    #pragma unroll
    for (int p=0;p<16;++p) yqp[p] = 0u;
    float u_part[8];
    #pragma unroll
    for (int k=0;k<8;++k) u_part[k] = 0.f;
    const u32* tp3 = tsum + (size_t)3*64;

    #pragma unroll 1
    for (int t=0; t<L_SEQ; ++t){
      float y = 0.f;
      if (t > 0){
        const u32 tag = (u32)(t-1);
        pollsum(tp3, tag);
        u32 rec[8];
        const u32* base = hb + (size_t)3*WIDTH;
        for(;;){
          #pragma unroll
          for (int k=0;k<8;++k) rec[k] = aload(base + 256*k + j);
          bool ok = true;
          #pragma unroll
          for (int k=0;k<8;++k) ok &= ((rec[k] >> 16) == tag);
          if (ok) break;
          __builtin_amdgcn_s_sleep(SLP_FAIL);
        }
        float yp = 0.f;
        #pragma unroll
        for (int k=0;k<8;++k) yp += w5f[k] * h2f(rec[k]);
        #pragma unroll
        for (int d=1; d<64; d<<=1) yp += __shfl_xor(yp, d);
        if (lw == 0) redp[w] = yp;
        __syncthreads();
        y = fmaxf(redp[0]+redp[1]+redp[2]+redp[3] + b5v, 0.f);
        if (X == 0 && j == 0) out[t-1] = y;
        yqp[15] |= (f2h(y) << 16);
      }
      uint4 c0v = c0p[(size_t)t*256 + j];
      {
        u32 c0h[4] = { c0v.x, c0v.y, c0v.z, c0v.w };
        float h0v[8];
        #pragma unroll
        for (int q=0;q<4;++q){
          h0v[2*q]   = fmaxf(h2f(c0h[q])       + u_part[2*q]   + w31v[2*q]*y,   0.f);
          h0v[2*q+1] = fmaxf(h2f(c0h[q] >> 16) + u_part[2*q+1] + w31v[2*q+1]*y, 0.f);
        }
        #pragma unroll
        for (int q=0;q<4;++q) hh[q] = f2h(h0v[2*q]) | (f2h(h0v[2*q+1]) << 16);
      }
      doreduce_emit((u32)t);
      // idle window: slide y-window, stream window weights, precompute u_part
      {
        #pragma unroll
        for (int p=0;p<15;++p) yqp[p] = (yqp[p] >> 16) | (yqp[p+1] << 16);
        yqp[15] = (yqp[15] >> 16);
        #pragma unroll
        for (int k=0;k<8;++k){
          float a = 0.f;
          #pragma unroll
          for (int p=0;p<16;++p)
            a = fdot2f(wyb[(size_t)(16*k+p)*256 + j], yqp[p], a);
          u_part[k] = a;
        }
      }
      for (int i=0;i<N_IDLE;++i) __builtin_amdgcn_s_sleep(SLP_IDLE);
    }

    // epilogue: y[L-1]
    if (X == 0){
      const u32 tag = (u32)(L_SEQ-1);
      pollsum(tp3, tag);
      u32 rec[8];
      const u32* base = hb + (size_t)3*WIDTH;
      for(;;){
        #pragma unroll
        for (int k=0;k<8;++k) rec[k] = aload(base + 256*k + j);
        bool ok = true;
        #pragma unroll
        for (int k=0;k<8;++k) ok &= ((rec[k] >> 16) == tag);
        if (ok) break;
        __builtin_amdgcn_s_sleep(SLP_FAIL);
      }
      float yp = 0.f;
      #pragma unroll
      for (int k=0;k<8;++k) yp += w5f[k] * h2f(rec[k]);
      #pragma unroll
      for (int d=1; d<64; d<<=1) yp += __shfl_xor(yp, d);
      if (lw == 0) redp[w] = yp;
      __syncthreads();
      if (j == 0) out[L_SEQ-1] = fmaxf(redp[0]+redp[1]+redp[2]+redp[3] + b5v, 0.f);
    }
  }
}

extern "C" void kernel_launch(void* const* d_in, const int* in_sizes, int n_in,
                              void* d_out, int out_size, void* d_ws, size_t ws_size,
                              hipStream_t stream) {
  (void)in_sizes; (void)n_in; (void)out_size; (void)ws_size;
  const int*   x  = (const int*)  d_in[0];
  const float* W0 = (const float*)d_in[1];
  const float* b0 = (const float*)d_in[2];
  const float* W1 = (const float*)d_in[3];
  const float* b1 = (const float*)d_in[4];
  const float* W2 = (const float*)d_in[5];
  const float* b2 = (const float*)d_in[6];
  const float* W3 = (const float*)d_in[7];
  const float* b3 = (const float*)d_in[8];
  const float* W4 = (const float*)d_in[9];
  const float* b4 = (const float*)d_in[10];
  const float* W5 = (const float*)d_in[11];
  const float* b5 = (const float*)d_in[12];
  float* out = (float*)d_out;
  char*  ws  = (char*)d_ws;

  // ws layout (16B-aligned), total ~47.9 MB
  constexpr size_t OFF_WP  = 0;                       // 4*2048*256*16 = 33,554,432
  constexpr size_t OFF_C0  = 33554432;                // 2048*256*16   =  8,388,608
  constexpr size_t OFF_W0T = 41943040;                // 704*2048*4    =  5,767,168
  constexpr size_t OFF_WY  = 47710208;                // 128*256*4     =    131,072
  constexpr size_t OFF_HB  = 47841280;                // 4*2048*4      =     32,768
  constexpr size_t OFF_TG  = 47874048;                // 4*64*4        =      1,024

  uint4* Wp  = (uint4*)(ws + OFF_WP);
  uint4* c0p = (uint4*)(ws + OFF_C0);
  float* W0T = (float*)(ws + OFF_W0T);
  u32*   wyb = (u32*)  (ws + OFF_WY);
  u32*   hb  = (u32*)  (ws + OFF_HB);
  u32*   tg  = (u32*)  (ws + OFF_TG);

  k_wt   <<<5632, 256, 0, stream>>>(W0, W0T);
  k_wc   <<<8192, 256, 0, stream>>>(W1, W2, W3, W4, Wp);
  k_c0   <<<2048, 256, 0, stream>>>(x, W0T, b0, c0p);
  k_wy   <<<128,  256, 0, stream>>>(W0, wyb);
  k_reset<<<32,   256, 0, stream>>>(hb, tg);
  k_main <<<NB,   256, 0, stream>>>(W0, b1, b2, b3, b4, W5, b5,
                                    Wp, c0p, wyb, hb, tg, out);
}

// Round 10
// 19659.615 us; speedup vs baseline: 1.9889x; 1.9889x over previous
//
#include <hip/hip_runtime.h>
#include <stdint.h>

// SequentialFeedForward: autoregressive 6-layer MLP, L=2048 steps.
// R10: stage-partitioned dataflow (4 groups x 64 blocks, 32 rows/block)
// with REPLICATED exchange regions + hot polling:
//  - h-hops: producers write each tagged u32 record (tag16|fp16) 16x, one
//    copy per 4-consumer cluster -> consumers hot-poll a private 8KB
//    replica (~4 pollers/region; ~12 req/us/line, uncontended)
//  - y-hop: G3 folds W5, wave0 replicates its tagged u64 partial 64x;
//    each G0 block hot-polls its private 512B, y reduced in-register per
//    wave (no LDS/barrier on y path)
//  - single barrier/step (red[] double-buffered by t&1)
// Model (R1-R9): per-line poll contention is catastrophic (R9: 180 req/us/
// line -> 2.3us RT); R4's polite shared polling paid ~1.2us in sweep-period
// + straggler phase. Replication buys hot detect at ~RT=0.35us.

typedef uint32_t u32;
typedef unsigned long long ull;
typedef _Float16 half_t;
typedef _Float16 half2_t __attribute__((ext_vector_type(2)));

#define L_SEQ 2048
#define WIDTH 2048
#define WS    32
#define NAA   21
#define INS   704   // WS*NAA + WS
#define NB    256
#define NREP  16    // h-record replication factor (4 consumers per replica)
#define SLP_IDLE 20 // ~0.53 us per unit
#define N_IDLE   3  // idle sleeps after emit

__device__ __forceinline__ float h2f(u32 b){
  union { unsigned short u; half_t h; } c; c.u = (unsigned short)(b & 0xffffu);
  return (float)c.h;
}
__device__ __forceinline__ u32 f2h(float f){
  union { unsigned short u; half_t h; } c; c.h = (half_t)f;
  return (u32)c.u;
}
__device__ __forceinline__ float fdot2f(u32 a, u32 b, float c){
#if __has_builtin(__builtin_amdgcn_fdot2)
  union { u32 u; half2_t v; } ca, cb; ca.u = a; cb.u = b;
  return __builtin_amdgcn_fdot2(ca.v, cb.v, c, false);
#else
  return c + h2f(a)*h2f(b) + h2f(a>>16)*h2f(b>>16);
#endif
}
__device__ __forceinline__ u32 aload(const u32* p){
  return __hip_atomic_load(const_cast<u32*>(p), __ATOMIC_RELAXED, __HIP_MEMORY_SCOPE_AGENT);
}
__device__ __forceinline__ void astore(u32* p, u32 v){
  __hip_atomic_store(p, v, __ATOMIC_RELAXED, __HIP_MEMORY_SCOPE_AGENT);
}
__device__ __forceinline__ ull aload64(const ull* p){
  return __hip_atomic_load(const_cast<ull*>(p), __ATOMIC_RELAXED, __HIP_MEMORY_SCOPE_AGENT);
}
__device__ __forceinline__ void astore64(ull* p, ull v){
  __hip_atomic_store(p, v, __ATOMIC_RELAXED, __HIP_MEMORY_SCOPE_AGENT);
}

// ---- pre-pass: transpose W0 (for coalesced c0 gather) ----
__global__ void k_wt(const float* __restrict__ W0, float* __restrict__ W0T){
  int tid = blockIdx.x*256 + threadIdx.x;
  if (tid < INS*WIDTH){
    int c = tid >> 11, i = tid & 2047;
    W0T[(size_t)c*WIDTH + i] = W0[(size_t)i*INS + c];
  }
}

// ---- pre-pass: W1..W4 fp32 -> fp16 ----
// Wp[(l*2048+r)*256 + j] uint4: comp q = half2(W[r][256*(2q)+j], W[r][256*(2q+1)+j])
__global__ void k_wc(const float* __restrict__ A, const float* __restrict__ B,
                     const float* __restrict__ C, const float* __restrict__ D,
                     uint4* __restrict__ Wp){
  int b = blockIdx.x; int l = b >> 11; int r = b & 2047; int j = threadIdx.x;
  const float* S = (l==0)?A:(l==1)?B:(l==2)?C:D;
  const float* row = S + (size_t)r*WIDTH;
  u32 o[4];
  #pragma unroll
  for (int q=0;q<4;++q)
    o[q] = f2h(row[256*(2*q)+j]) | (f2h(row[256*(2*q+1)+j]) << 16);
  Wp[(size_t)b*256 + j] = make_uint4(o[0],o[1],o[2],o[3]);
}

// ---- pre-pass: c0[t][col] = b0 + one-hot gather; thread j owns cols {256k+j} ----
__global__ void k_c0(const int* __restrict__ x, const float* __restrict__ W0T,
                     const float* __restrict__ b0, uint4* __restrict__ c0p){
  int t = blockIdx.x, j = threadIdx.x;
  __shared__ int cidx[WS];
  if (j < WS){
    int s = t - (WS-1) + j;
    cidx[j] = (s >= 0) ? (NAA*j + x[s]) : -1;
  }
  __syncthreads();
  float acc[8];
  #pragma unroll
  for (int k=0;k<8;++k) acc[k] = b0[256*k + j];
  for (int m=0;m<WS;++m){
    int c = cidx[m];
    if (c >= 0){
      const float* col = W0T + (size_t)c*WIDTH;
      #pragma unroll
      for (int k=0;k<8;++k) acc[k] += col[256*k + j];
    }
  }
  u32 o[4];
  #pragma unroll
  for (int q=0;q<4;++q) o[q] = f2h(acc[2*q]) | (f2h(acc[2*q+1]) << 16);
  c0p[(size_t)t*256 + j] = make_uint4(o[0],o[1],o[2],o[3]);
}

// ---- pre-pass: window weights for G0's idle-window streaming ----
__global__ void k_wy(const float* __restrict__ W0, u32* __restrict__ wyb){
  int b = blockIdx.x; int k = b >> 4, p = b & 15; int j = threadIdx.x;
  int col = 256*k + j;
  float a = W0[(size_t)col*INS + (INS-WS) + 2*p];
  float c = W0[(size_t)col*INS + (INS-WS) + 2*p + 1];
  wyb[(size_t)b*256 + j] = f2h(a) | (f2h(c) << 16);
}

// ---- pre-pass: reset exchange buffers (every launch: replay-safe) ----
// hr: 3 hop buffers x NREP x 2048 u32 = 98304; pr: 64 x 64 u64 = 8192 u32
__global__ void k_reset(u32* __restrict__ hr, u32* __restrict__ pr){
  int tid = blockIdx.x*256 + threadIdx.x;
  if (tid < 3*NREP*2048) hr[tid] = 0xFFFFFFFFu;
  if (tid < 8192)        pr[tid] = 0xFFFFFFFFu;
}

// ---- main persistent dataflow kernel ----
__global__ __launch_bounds__(256, 1) void k_main(
    const float* __restrict__ W0,
    const float* __restrict__ b1, const float* __restrict__ b2,
    const float* __restrict__ b3, const float* __restrict__ b4,
    const float* __restrict__ W5, const float* __restrict__ b5p,
    const uint4* __restrict__ Wp, const uint4* __restrict__ c0p,
    const u32* __restrict__ wyb,
    u32* hrep, ull* prep, float* __restrict__ out)
{
  const int j  = threadIdx.x;
  const int X  = blockIdx.x;
  const int g  = X >> 6;      // stage group 0..3
  const int Xl = X & 63;      // block within group
  const int lw = j & 63;
  const int w  = j >> 6;
  const int r  = j & 31;

  __shared__ float red[2][4][32];   // double-buffered by t&1
  __shared__ float bias_lds[32];

  // stage weight slice: rows 32*Xl .. 32*Xl+31 of W_{g+1}
  uint4 wreg[32];
  #pragma unroll
  for (int i=0;i<32;++i)
    wreg[i] = Wp[((size_t)g*2048 + 32*Xl + i)*256 + j];

  const float* bp = (g==0)?b1:(g==1)?b2:(g==2)?b3:b4;
  if (j < 32) bias_lds[j] = bp[32*Xl + j];
  float w5r = 0.f;
  if (g == 3) w5r = W5[32*Xl + r];

  u32 hh[4];

  // dots over this thread's 8 columns + merged butterfly -> red[buf][w][row]
  auto dotsbfly = [&](int buf){
    float c32[32];
    #pragma unroll
    for (int i=0;i<32;++i){
      float a = 0.f;
      a = fdot2f(wreg[i].x, hh[0], a);
      a = fdot2f(wreg[i].y, hh[1], a);
      a = fdot2f(wreg[i].z, hh[2], a);
      a = fdot2f(wreg[i].w, hh[3], a);
      c32[i] = a;
    }
    float c16[16];
    #pragma unroll
    for (int i=0;i<16;++i){
      float v = c32[2*i]   + __shfl_xor(c32[2*i],   1);
      float u = c32[2*i+1] + __shfl_xor(c32[2*i+1], 1);
      c16[i] = (lw & 1) ? u : v;
    }
    float c8[8];
    #pragma unroll
    for (int i=0;i<8;++i){
      float v = c16[2*i]   + __shfl_xor(c16[2*i],   2);
      float u = c16[2*i+1] + __shfl_xor(c16[2*i+1], 2);
      c8[i] = (lw & 2) ? u : v;
    }
    float c4[4];
    #pragma unroll
    for (int i=0;i<4;++i){
      float v = c8[2*i]   + __shfl_xor(c8[2*i],   4);
      float u = c8[2*i+1] + __shfl_xor(c8[2*i+1], 4);
      c4[i] = (lw & 4) ? u : v;
    }
    float c2[2];
    #pragma unroll
    for (int i=0;i<2;++i){
      float v = c4[2*i]   + __shfl_xor(c4[2*i],   8);
      float u = c4[2*i+1] + __shfl_xor(c4[2*i+1], 8);
      c2[i] = (lw & 8) ? u : v;
    }
    float v1 = c2[0] + __shfl_xor(c2[0], 16);
    float u1 = c2[1] + __shfl_xor(c2[1], 16);
    float c1 = (lw & 16) ? u1 : v1;
    float tot = c1 + __shfl_xor(c1, 32);
    if (lw < 32) red[buf][w][lw] = tot;
  };

  // hot poll of this block's private replica (tag+payload same word)
  auto pollrec = [&](const u32* base, u32 tag, u32 (&rec)[8]){
    for(;;){
      #pragma unroll
      for (int k=0;k<8;++k) rec[k] = aload(base + 256*k);
      bool ok = true;
      #pragma unroll
      for (int k=0;k<8;++k) ok &= ((rec[k] >> 16) == tag);
      if (ok) break;
    }
  };

  // stagger pipeline-fill polling
  for (int i=0;i<g;++i) __builtin_amdgcn_s_sleep(SLP_IDLE);

  if (g == 3){
    // ---- G3: layer 4 + W5 partial fold; replicate tagged u64 partial 64x ----
    const u32* base = hrep + ((size_t)2*NREP + (Xl>>2))*2048 + j;
    #pragma unroll 1
    for (int t=0; t<L_SEQ; ++t){
      const int buf = t & 1;
      u32 rec[8];
      pollrec(base, (u32)t, rec);
      #pragma unroll
      for (int q=0;q<4;++q) hh[q] = (rec[2*q] & 0xffffu) | (rec[2*q+1] << 16);
      dotsbfly(buf);
      __syncthreads();
      float s = fmaxf(red[buf][0][r]+red[buf][1][r]+red[buf][2][r]+red[buf][3][r]
                      + bias_lds[r], 0.f);
      float pp = s * w5r;
      pp += __shfl_xor(pp, 1);
      pp += __shfl_xor(pp, 2);
      pp += __shfl_xor(pp, 4);
      pp += __shfl_xor(pp, 8);
      pp += __shfl_xor(pp, 16);
      if (w == 0)
        astore64(prep + (size_t)lw*64 + Xl,
                 ((ull)(u32)t << 32) | (ull)__float_as_uint(pp));
      for (int i=0;i<N_IDLE;++i) __builtin_amdgcn_s_sleep(SLP_IDLE);
    }
  } else if (g > 0){
    // ---- G1/G2: layers 2,3; emit 16 replicas ----
    const u32* base = hrep + ((size_t)(g-1)*NREP + (Xl>>2))*2048 + j;
    u32* dst = hrep + (size_t)g*NREP*2048;
    #pragma unroll 1
    for (int t=0; t<L_SEQ; ++t){
      const int buf = t & 1;
      u32 rec[8];
      pollrec(base, (u32)t, rec);
      #pragma unroll
      for (int q=0;q<4;++q) hh[q] = (rec[2*q] & 0xffffu) | (rec[2*q+1] << 16);
      dotsbfly(buf);
      __syncthreads();
      float s = fmaxf(red[buf][0][r]+red[buf][1][r]+red[buf][2][r]+red[buf][3][r]
                      + bias_lds[r], 0.f);
      u32 rv = ((u32)t << 16) | f2h(s);
      astore(dst + (size_t)((j>>5)    )*2048 + 32*Xl + r, rv);
      astore(dst + (size_t)((j>>5) + 8)*2048 + 32*Xl + r, rv);
      for (int i=0;i<N_IDLE;++i) __builtin_amdgcn_s_sleep(SLP_IDLE);
    }
  } else {
    // ---- G0: y from replicated partials + h0 window + layer 1 ----
    float w31v[8];
    #pragma unroll
    for (int k=0;k<8;++k)
      w31v[k] = W0[(size_t)(256*k + j)*INS + (INS-1)];
    const float b5v = b5p[0];
    u32 yqp[16];
    #pragma unroll
    for (int p=0;p<16;++p) yqp[p] = 0u;
    float u_part[8];
    #pragma unroll
    for (int k=0;k<8;++k) u_part[k] = 0.f;
    const ull* yb = prep + (size_t)Xl*64 + lw;  // private 512B region
    u32* dst = hrep;  // hop buffer 0

    #pragma unroll 1
    for (int t=0; t<L_SEQ; ++t){
      const int buf = t & 1;
      uint4 c0v = c0p[(size_t)t*256 + j];
      float y = 0.f;
      if (t > 0){
        const u32 tag = (u32)(t-1);
        ull v;
        for(;;){ v = aload64(yb); if ((u32)(v >> 32) == tag) break; }
        float p = __uint_as_float((u32)v);
        #pragma unroll
        for (int d=1; d<64; d<<=1) p += __shfl_xor(p, d);
        y = fmaxf(p + b5v, 0.f);
        if (X == 0 && j == 0) out[t-1] = y;
        yqp[15] |= (f2h(y) << 16);
      }
      // h0 cols {256k+j} = relu(c0 + u_part + w31*y)
      {
        u32 c0h[4] = { c0v.x, c0v.y, c0v.z, c0v.w };
        float h0v[8];
        #pragma unroll
        for (int q=0;q<4;++q){
          h0v[2*q]   = fmaxf(h2f(c0h[q])       + u_part[2*q]   + w31v[2*q]*y,   0.f);
          h0v[2*q+1] = fmaxf(h2f(c0h[q] >> 16) + u_part[2*q+1] + w31v[2*q+1]*y, 0.f);
        }
        #pragma unroll
        for (int q=0;q<4;++q) hh[q] = f2h(h0v[2*q]) | (f2h(h0v[2*q+1]) << 16);
      }
      dotsbfly(buf);
      __syncthreads();
      float s = fmaxf(red[buf][0][r]+red[buf][1][r]+red[buf][2][r]+red[buf][3][r]
                      + bias_lds[r], 0.f);
      u32 rv = ((u32)t << 16) | f2h(s);
      astore(dst + (size_t)((j>>5)    )*2048 + 32*Xl + r, rv);
      astore(dst + (size_t)((j>>5) + 8)*2048 + 32*Xl + r, rv);
      // idle window: slide y-window, stream window weights, precompute u_part
      {
        #pragma unroll
        for (int p=0;p<15;++p) yqp[p] = (yqp[p] >> 16) | (yqp[p+1] << 16);
        yqp[15] = (yqp[15] >> 16);
        #pragma unroll
        for (int k=0;k<8;++k){
          float a = 0.f;
          #pragma unroll
          for (int p=0;p<16;++p)
            a = fdot2f(wyb[(size_t)(16*k+p)*256 + j], yqp[p], a);
          u_part[k] = a;
        }
      }
      for (int i=0;i<N_IDLE;++i) __builtin_amdgcn_s_sleep(SLP_IDLE);
    }

    // epilogue: y[L-1]
    if (X == 0 && j < 64){
      const u32 tag = (u32)(L_SEQ-1);
      ull v;
      for(;;){ v = aload64(yb); if ((u32)(v >> 32) == tag) break; }
      float p = __uint_as_float((u32)v);
      #pragma unroll
      for (int d=1; d<64; d<<=1) p += __shfl_xor(p, d);
      if (j == 0) out[L_SEQ-1] = fmaxf(p + b5v, 0.f);
    }
  }
}

extern "C" void kernel_launch(void* const* d_in, const int* in_sizes, int n_in,
                              void* d_out, int out_size, void* d_ws, size_t ws_size,
                              hipStream_t stream) {
  (void)in_sizes; (void)n_in; (void)out_size; (void)ws_size;
  const int*   x  = (const int*)  d_in[0];
  const float* W0 = (const float*)d_in[1];
  const float* b0 = (const float*)d_in[2];
  const float* W1 = (const float*)d_in[3];
  const float* b1 = (const float*)d_in[4];
  const float* W2 = (const float*)d_in[5];
  const float* b2 = (const float*)d_in[6];
  const float* W3 = (const float*)d_in[7];
  const float* b3 = (const float*)d_in[8];
  const float* W4 = (const float*)d_in[9];
  const float* b4 = (const float*)d_in[10];
  const float* W5 = (const float*)d_in[11];
  const float* b5 = (const float*)d_in[12];
  float* out = (float*)d_out;
  char*  ws  = (char*)d_ws;

  // ws layout (16B-aligned). HR/PR live inside W0T's region: W0T is only
  // read by k_c0, which completes (stream-ordered) before k_reset writes.
  constexpr size_t OFF_WP  = 0;                       // 4*2048*256*16 = 33,554,432
  constexpr size_t OFF_C0  = 33554432;                // 2048*256*16   =  8,388,608
  constexpr size_t OFF_W0T = 41943040;                // 704*2048*4    =  5,767,168
  constexpr size_t OFF_HR  = 41943040;                // 3*16*2048*4   =    393,216
  constexpr size_t OFF_PR  = 42336256;                // 64*64*8       =     32,768
  constexpr size_t OFF_WY  = 47710208;                // 128*256*4     =    131,072

  uint4* Wp  = (uint4*)(ws + OFF_WP);
  uint4* c0p = (uint4*)(ws + OFF_C0);
  float* W0T = (float*)(ws + OFF_W0T);
  u32*   hr  = (u32*)  (ws + OFF_HR);
  u32*   pr  = (u32*)  (ws + OFF_PR);
  ull*   prq = (ull*)  (ws + OFF_PR);
  u32*   wyb = (u32*)  (ws + OFF_WY);

  k_wt   <<<5632, 256, 0, stream>>>(W0, W0T);
  k_wc   <<<8192, 256, 0, stream>>>(W1, W2, W3, W4, Wp);
  k_c0   <<<2048, 256, 0, stream>>>(x, W0T, b0, c0p);
  k_wy   <<<128,  256, 0, stream>>>(W0, wyb);
  k_reset<<<384,  256, 0, stream>>>(hr, pr);
  k_main <<<NB,   256, 0, stream>>>(W0, b1, b2, b3, b4, W5, b5,
                                    Wp, c0p, wyb, hr, prq, out);
}